// Round 3
// baseline (7683.337 us; speedup 1.0000x reference)
//
#include <hip/hip_runtime.h>

// Problem constants (fixed by reference setup_inputs)
#define BB   2048   // batch
#define LL   20     // seq length
#define JJ   25     // joints
#define CC   256    // channels
#define FF   64     // filters
#define KK   4      // hops
#define JPAD 28     // padded row length for aligned float4 reads of M rows
#define NQ   52     // persistent blocks per l  (20*52 = 1040 blocks ~ 1024 resident)
#define NB2  (BB/2) // 1024 slab-pairs per l

typedef float f2 __attribute__((ext_vector_type(2)));
typedef float f4 __attribute__((ext_vector_type(4)));

// out[l,b,i,c] = sum_j M[l,i,j] * x[b,l,j,c]
// M[l,i,j]     = sum_k w[k,l] * A[i,j]^k   (elementwise power, Horner)
// w[k,l]       = sum_n kernel[n,k,l]
//
// Persistent blocks: block (l,q) builds M ONCE, then processes slab-pairs
// b2 = q, q+NQ, ... < 1024 for that same l. Amortizes the preamble ~20x
// and keeps the read/write streams continuous across slabs.
__global__ __launch_bounds__(256, 4) void GCNLayer_72602127172024_kernel(
    const float* __restrict__ x,     // [B,L,J,C]
    const float* __restrict__ A,     // [J,J]
    const float* __restrict__ kern,  // [F,K,L]
    float* __restrict__ out)         // [L,B,J,C]
{
    __shared__ float w_sh[KK];
    __shared__ __align__(16) float Ms[JJ * JPAD];  // Ms[i*JPAD+j], pad zeroed

    const int tid = threadIdx.x;
    const int l   = blockIdx.x / NQ;   // uniform -> scalar div
    const int q   = blockIdx.x - l * NQ;

    // ---- w[k] = sum_n kern[n*K*L + k*L + l]; wave k handles hop k, lane = n ----
    {
        const int k    = tid >> 6;   // wave id == hop (KK==4 waves exactly)
        const int lane = tid & 63;   // filter index (FF==64 exactly)
        float v = kern[lane * (KK * LL) + k * LL + l];
        v += __shfl_xor(v, 32, 64);
        v += __shfl_xor(v, 16, 64);
        v += __shfl_xor(v, 8, 64);
        v += __shfl_xor(v, 4, 64);
        v += __shfl_xor(v, 2, 64);
        v += __shfl_xor(v, 1, 64);
        if (lane == 0) w_sh[k] = v;
    }
    __syncthreads();

    const float w0 = w_sh[0], w1 = w_sh[1], w2 = w_sh[2], w3 = w_sh[3];

    // ---- build Ms[i][j] once (row-major, padded); pad entries set to 0 ----
    for (int e = tid; e < JJ * JPAD; e += 256) {
        const int i = e / JPAD;
        const int j = e - i * JPAD;
        float m = 0.0f;
        if (j < JJ) {
            const float a = A[i * JJ + j];
            m = w0 + a * (w1 + a * (w2 + a * w3));   // Horner; a=0 -> w0 (0^0==1)
        }
        Ms[e] = m;
    }
    __syncthreads();

    // ---- persistent slab loop: 2 batches x 128 float2 columns per iteration ----
    const int bsub = tid >> 7;        // 0..1
    const int c2   = tid & 127;       // float2 column (CC/2 == 128)

    for (int b2 = q; b2 < NB2; b2 += NQ) {
        const int b = (b2 << 1) + bsub;

        const f2* __restrict__ xin =
            reinterpret_cast<const f2*>(x) + ((b * LL + l) * JJ) * 128 + c2;
        f2* __restrict__ oout =
            reinterpret_cast<f2*>(out) + ((l * BB + b) * JJ) * 128 + c2;

        // Full [J] column slab into registers (25 x f2 = 50 VGPR), coalesced
        // 512B/wave-instr. Nontemporal: pure stream, no reuse.
        f2 xv[JJ];
#pragma unroll
        for (int j = 0; j < JJ; ++j)
            xv[j] = __builtin_nontemporal_load(xin + j * 128);

        // Per output joint i: M row i = 7 float4 LDS broadcasts (uniform
        // address -> conflict-free), accumulate, store immediately.
#pragma unroll
        for (int i = 0; i < JJ; ++i) {
            const f4* mrow = reinterpret_cast<const f4*>(Ms + i * JPAD);
            f2 acc = {0.0f, 0.0f};
#pragma unroll
            for (int j4 = 0; j4 < 7; ++j4) {
                const f4 m4 = mrow[j4];
#pragma unroll
                for (int comp = 0; comp < 4; ++comp) {
                    const int j = j4 * 4 + comp;
                    if (j < JJ) {   // compile-time pruned (full unroll)
                        const float m = m4[comp];
                        acc.x = fmaf(m, xv[j].x, acc.x);
                        acc.y = fmaf(m, xv[j].y, acc.y);
                    }
                }
            }
            __builtin_nontemporal_store(acc, oout + i * 128);
        }
    }
}

extern "C" void kernel_launch(void* const* d_in, const int* in_sizes, int n_in,
                              void* d_out, int out_size, void* d_ws, size_t ws_size,
                              hipStream_t stream) {
    const float* x    = (const float*)d_in[0];   // [B,L,J,C]
    const float* A    = (const float*)d_in[1];   // [J,J]
    const float* kern = (const float*)d_in[2];   // [F,K,L]
    float* out        = (float*)d_out;           // [L,B,J,C]

    const int grid = LL * NQ;  // 1040 persistent blocks
    GCNLayer_72602127172024_kernel<<<grid, 256, 0, stream>>>(x, A, kern, out);
}

// Round 4
// 389.949 us; speedup vs baseline: 19.7034x; 19.7034x over previous
//
#include <hip/hip_runtime.h>

// Problem constants (fixed by reference setup_inputs)
#define BB   2048   // batch
#define LL   20     // seq length
#define JJ   25     // joints
#define CC   256    // channels
#define FF   64     // filters
#define KK   4      // hops
#define JPAD 28     // padded row length for aligned float4 reads of M rows
#define MSZ  (JJ * JPAD)   // 700 floats per l-slice of M

typedef float f2 __attribute__((ext_vector_type(2)));
typedef float f4 __attribute__((ext_vector_type(4)));

// ---------------------------------------------------------------------------
// Kernel 1 (tiny): M[l,i,j] = sum_k w[k,l] * A[i,j]^k,  w[k,l] = sum_n kern[n,k,l]
// One block per l; writes [LL][JJ][JPAD] floats (pad zeroed) into d_ws.
// ---------------------------------------------------------------------------
__global__ __launch_bounds__(256) void GCN_precompute_M(
    const float* __restrict__ A,     // [J,J]
    const float* __restrict__ kern,  // [F,K,L]
    float* __restrict__ Mg)          // [LL][JJ][JPAD]
{
    const int l = blockIdx.x;
    __shared__ float w_sh[KK];

    {
        const int k    = threadIdx.x >> 6;   // wave id == hop (KK==4 waves)
        const int lane = threadIdx.x & 63;   // filter index (FF==64 exactly)
        float v = kern[lane * (KK * LL) + k * LL + l];
        v += __shfl_xor(v, 32, 64);
        v += __shfl_xor(v, 16, 64);
        v += __shfl_xor(v, 8, 64);
        v += __shfl_xor(v, 4, 64);
        v += __shfl_xor(v, 2, 64);
        v += __shfl_xor(v, 1, 64);
        if (lane == 0) w_sh[k] = v;
    }
    __syncthreads();

    const float w0 = w_sh[0], w1 = w_sh[1], w2 = w_sh[2], w3 = w_sh[3];

    for (int e = threadIdx.x; e < MSZ; e += 256) {
        const int i = e / JPAD;
        const int j = e - i * JPAD;
        float m = 0.0f;
        if (j < JJ) {
            const float a = A[i * JJ + j];
            m = w0 + a * (w1 + a * (w2 + a * w3));   // Horner; a=0 -> w0 (0^0==1)
        }
        Mg[l * MSZ + e] = m;
    }
}

// ---------------------------------------------------------------------------
// Kernel 2 (hot, round-2 structure): straight-line, one slab-pair per block.
// Grid: LL * (BB/2); block = 256 threads = 2 batch-subs x 128 float2 cols.
// Preamble is now just 175 f4 L2 loads + one barrier.
// ---------------------------------------------------------------------------
__global__ __launch_bounds__(256, 4) void GCNLayer_72602127172024_kernel(
    const float* __restrict__ x,     // [B,L,J,C]
    const float* __restrict__ Mg,    // [LL][JJ][JPAD]
    float* __restrict__ out)         // [L,B,J,C]
{
    __shared__ __align__(16) float Ms[MSZ];  // Ms[i*JPAD+j], pad already zeroed

    const int tid = threadIdx.x;
    const int gid = blockIdx.x;
    const int l   = gid >> 10;          // / (BB/2) == /1024
    const int bb  = (gid & 1023) << 1;  // base batch of this block

    // ---- stage M l-slice: 700 floats = 175 f4, coalesced, L2-resident ----
    {
        const f4* __restrict__ src = reinterpret_cast<const f4*>(Mg + l * MSZ);
        f4* dst = reinterpret_cast<f4*>(Ms);
        if (tid < MSZ / 4) dst[tid] = src[tid];
    }
    __syncthreads();

    // ---- main: each thread owns one float2 column of one (b,l) slab ----
    const int bsub = tid >> 7;        // 0..1
    const int c2   = tid & 127;       // float2 column (CC/2 == 128)
    const int b    = bb + bsub;

    const f2* __restrict__ xin =
        reinterpret_cast<const f2*>(x) + ((b * LL + l) * JJ) * 128 + c2;
    f2* __restrict__ oout =
        reinterpret_cast<f2*>(out) + ((l * BB + b) * JJ) * 128 + c2;

    // Full [J] column slab into registers (25 x f2 = 50 VGPR), coalesced
    // 512B/wave-instr. Nontemporal: pure stream, no reuse.
    f2 xv[JJ];
#pragma unroll
    for (int j = 0; j < JJ; ++j)
        xv[j] = __builtin_nontemporal_load(xin + j * 128);

    // Per output joint i: M row i = 7 float4 LDS broadcasts (uniform
    // address -> conflict-free), accumulate, store immediately.
#pragma unroll
    for (int i = 0; i < JJ; ++i) {
        const f4* mrow = reinterpret_cast<const f4*>(Ms + i * JPAD);
        f2 acc = {0.0f, 0.0f};
#pragma unroll
        for (int j4 = 0; j4 < 7; ++j4) {
            const f4 m4 = mrow[j4];
#pragma unroll
            for (int comp = 0; comp < 4; ++comp) {
                const int j = j4 * 4 + comp;
                if (j < JJ) {   // compile-time pruned (full unroll)
                    const float m = m4[comp];
                    acc.x = fmaf(m, xv[j].x, acc.x);
                    acc.y = fmaf(m, xv[j].y, acc.y);
                }
            }
        }
        __builtin_nontemporal_store(acc, oout + i * 128);
    }
}

extern "C" void kernel_launch(void* const* d_in, const int* in_sizes, int n_in,
                              void* d_out, int out_size, void* d_ws, size_t ws_size,
                              hipStream_t stream) {
    const float* x    = (const float*)d_in[0];   // [B,L,J,C]
    const float* A    = (const float*)d_in[1];   // [J,J]
    const float* kern = (const float*)d_in[2];   // [F,K,L]
    float* out        = (float*)d_out;           // [L,B,J,C]
    float* Mg         = (float*)d_ws;            // [LL][JJ][JPAD] = 56 KB

    GCN_precompute_M<<<LL, 256, 0, stream>>>(A, kern, Mg);

    const int grid = LL * (BB / 2);  // 20480 blocks
    GCNLayer_72602127172024_kernel<<<grid, 256, 0, stream>>>(x, Mg, out);
}